// Round 13
// baseline (4313.641 us; speedup 1.0000x reference)
//
#include <hip/hip_runtime.h>
#include <stdint.h>

typedef unsigned short ushort_t;
typedef __bf16 bf16x8 __attribute__((ext_vector_type(8)));
typedef float f32x4 __attribute__((ext_vector_type(4)));

// ---------- bf16 <-> f32 (bit ops) ----------
__device__ __forceinline__ float b2f(ushort_t u) {
  union { unsigned u; float f; } v; v.u = ((unsigned)u) << 16; return v.f;
}
__device__ __forceinline__ ushort_t f2b(float f) {
  union { float f; unsigned u; } v; v.f = f;
  unsigned r = (v.u + 0x7FFFu + ((v.u >> 16) & 1u)) >> 16;
  return (ushort_t)r;
}

// ---------- fast transcendentals (HW v_exp_f32 based) ----------
__device__ __forceinline__ float sigm(float x)     { return 1.f / (1.f + __expf(-x)); }
__device__ __forceinline__ float tanhfast(float x) { return 1.f - 2.f / (1.f + __expf(2.f * x)); }

// ---------- device-coherent write-through stores (visible at MALL) ----------
__device__ __forceinline__ void store_short_wt(ushort_t* p, ushort_t v) {
  asm volatile("global_store_short %0, %1, off sc0 sc1"
               :: "v"(p), "v"((unsigned)v) : "memory");
}
__device__ __forceinline__ void store_uint_wt(unsigned* p, unsigned v) {
  asm volatile("global_store_dword %0, %1, off sc0 sc1"
               :: "v"(p), "v"(v) : "memory");
}

// ---------- global -> LDS direct load, 16B per lane ----------
__device__ __forceinline__ void gload_lds16(const void* g, void* lds) {
  auto l3 = reinterpret_cast<__attribute__((address_space(3))) unsigned*>(
      reinterpret_cast<uintptr_t>(lds));
  __builtin_amdgcn_global_load_lds(reinterpret_cast<const unsigned*>(g), l3, 16, 0, 0);
}

// =====================================================================
// 256x256-tile GEMM (r12-proven): C = A@B^T + bias0 + bias1.
// =====================================================================
template <bool F32OUT>
__global__ __launch_bounds__(512) void gemm_bt(
    const ushort_t* __restrict__ A, const ushort_t* __restrict__ B,
    void* __restrict__ Cv,
    const float* __restrict__ bias0, const float* __restrict__ bias1,
    int lda, int ldb, long ldc, int Kpad, int N)
{
  __shared__ alignas(16) ushort_t As[256 * 32];
  __shared__ alignas(16) ushort_t Bs[256 * 32];
  const int tid = threadIdx.x;
  const int w = tid >> 6, l = tid & 63;
  const int wr = w >> 2, wc = w & 3;

  unsigned nwg = gridDim.x * gridDim.y;
  unsigned wg = blockIdx.y * gridDim.x + blockIdx.x;
  {
    unsigned q = nwg >> 3, r = nwg & 7u;
    unsigned xcd = wg & 7u, idx = wg >> 3;
    wg = (xcd < r ? xcd * (q + 1) : r * (q + 1) + (xcd - r) * q) + idx;
  }
  const long m0 = (long)(wg % gridDim.x) * 256;
  const long n0 = (long)(wg / gridDim.x) * 256;

  const int lrow = l & 15, hi = l >> 4, lk = hi * 8;

  f32x4 acc[8][4] = {};

  const int c0 = tid, c1 = tid + 512;
  const int r0 = c0 >> 2, g0 = (c0 & 3) * 8;
  const int r1 = c1 >> 2, g1 = (c1 & 3) * 8;

  for (int k0 = 0; k0 < Kpad; k0 += 32) {
    gload_lds16(A + (m0 + r0) * lda + k0 + g0, As + c0 * 8);
    gload_lds16(A + (m0 + r1) * lda + k0 + g1, As + c1 * 8);
    gload_lds16(B + (n0 + r0) * ldb + k0 + g0, Bs + c0 * 8);
    gload_lds16(B + (n0 + r1) * ldb + k0 + g1, Bs + c1 * 8);
    __syncthreads();

    bf16x8 af[8], bfr[4];
#pragma unroll
    for (int mi = 0; mi < 8; mi++)
      af[mi] = *(const bf16x8*)(As + (wr * 128 + mi * 16 + lrow) * 32 + lk);
#pragma unroll
    for (int ni = 0; ni < 4; ni++)
      bfr[ni] = *(const bf16x8*)(Bs + (wc * 64 + ni * 16 + lrow) * 32 + lk);
#pragma unroll
    for (int mi = 0; mi < 8; mi++)
#pragma unroll
      for (int ni = 0; ni < 4; ni++)
        acc[mi][ni] = __builtin_amdgcn_mfma_f32_16x16x32_bf16(af[mi], bfr[ni], acc[mi][ni], 0, 0, 0);
    __syncthreads();
  }

  const int rbase = hi * 4;
#pragma unroll
  for (int ni = 0; ni < 4; ni++) {
    int gcol = (int)n0 + wc * 64 + ni * 16 + lrow;
    if (gcol < N) {
      float badd = 0.f;
      if (bias0) badd += bias0[gcol];
      if (bias1) badd += bias1[gcol];
#pragma unroll
      for (int mi = 0; mi < 8; mi++) {
#pragma unroll
        for (int r = 0; r < 4; r++) {
          long grow = m0 + wr * 128 + mi * 16 + rbase + r;
          float v = acc[mi][ni][r] + badd;
          if (F32OUT) ((float*)Cv)[grow * ldc + gcol] = v;
          else        ((ushort_t*)Cv)[grow * ldc + gcol] = f2b(v);
        }
      }
    }
  }
}

// =====================================================================
// FUSED 3-layer pipelined LSTM: 216 blocks = 3 layers x 72 unit-slices.
// Layer 0 uses precomputed G0 (= x0@Wih0^T + biases). Layers 1,2 compute
// the x@Wih^T contribution on the fly (x row = hs_prev[t+1], gated on the
// prev layer's flag >= t+1) with Wih fragments streamed from L2.
// Cross-layer pipeline: critical path 102 steps instead of 300.
// Same proven transport: write-through h, per-slice monotonic flags,
// low-traffic snapshot polling (r10). Whh slice in 144KB LDS.
// =====================================================================
__global__ __launch_bounds__(256) void lstm_fused3(
    ushort_t* __restrict__ hs0, ushort_t* __restrict__ hs1, ushort_t* __restrict__ hs2,
    const ushort_t* __restrict__ G0,
    const ushort_t* __restrict__ Whp0, const ushort_t* __restrict__ Whp1,
    const ushort_t* __restrict__ Whp2,
    const ushort_t* __restrict__ Wip1, const ushort_t* __restrict__ Wip2,
    const float* __restrict__ c0, const float* __restrict__ c1, const float* __restrict__ c2,
    const float* __restrict__ bi1, const float* __restrict__ bh1,
    const float* __restrict__ bi2, const float* __restrict__ bh2,
    unsigned* __restrict__ flags)    // [3][72] lines of 128B, zeroed
{
  extern __shared__ ushort_t Bsh[];   // Whh slice: 4*16*144 chunks = 147456 B
  const int tid = threadIdx.x;
  const int w = tid >> 6, l = tid & 63;
  const int L  = blockIdx.x / 72;
  const int us = blockIdx.x % 72;
  const int lrow = l & 15, hi = l >> 4, lk = hi * 8;
  const int u = us * 16 + lrow;
  const int usafe = (u < 1150) ? u : 0;
  const int row0 = w * 16 + hi * 4;
  const int x7 = lrow & 7;
  const int start = us >> 1;

  ushort_t* hsL = (L == 0) ? hs0 : (L == 1) ? hs1 : hs2;
  const ushort_t* hsP = (L == 1) ? hs0 : hs1;            // unused for L==0
  const ushort_t* Whh = (L == 0) ? Whp0 : (L == 1) ? Whp1 : Whp2;
  const ushort_t* Wih = (L == 1) ? Wip1 : Wip2;          // unused for L==0
  const float* cin = (L == 0) ? c0 : (L == 1) ? c1 : c2;
  unsigned* fown  = flags + L * 2304;                    // 72*32 words
  unsigned* fprev = flags + (L - 1) * 2304;              // valid for L>0

  // per-gate bias (trailing layers only)
  float bias4[4] = {0.f, 0.f, 0.f, 0.f};
  if (L > 0) {
    const float* bi = (L == 1) ? bi1 : bi2;
    const float* bh = (L == 1) ? bh1 : bh2;
#pragma unroll
    for (int g = 0; g < 4; ++g) bias4[g] = bi[g * 1150 + usafe] + bh[g * 1150 + usafe];
  }

  // ---- stage Whh slice into LDS (once), chunk-swizzled: phys = c ^ (row&7) ----
  for (int ci = tid; ci < 9216; ci += 256) {
    int gate = ci / 2304;
    int rem  = ci - gate * 2304;
    int row  = rem / 144;
    int c    = rem - row * 144;
    bf16x8 v = *(const bf16x8*)(Whh + ((long)(gate * 1150 + us * 16 + row)) * 1152 + c * 8);
    *(bf16x8*)(Bsh + (((gate * 16 + row) * 144) + (c ^ (row & 7))) * 8) = v;
  }
  const ushort_t* Bg0 = Bsh + ((0 * 16 + lrow) * 144) * 8;
  const ushort_t* Bg1 = Bsh + ((1 * 16 + lrow) * 144) * 8;
  const ushort_t* Bg2 = Bsh + ((2 * 16 + lrow) * 144) * 8;
  const ushort_t* Bg3 = Bsh + ((3 * 16 + lrow) * 144) * 8;

  // Wih per-gate row pointers (trailing layers)
  const ushort_t* wi0 = Wih + ((long)(0 * 1150 + us * 16 + lrow)) * 1152 + lk;
  const ushort_t* wi1 = Wih + ((long)(1 * 1150 + us * 16 + lrow)) * 1152 + lk;
  const ushort_t* wi2 = Wih + ((long)(2 * 1150 + us * 16 + lrow)) * 1152 + lk;
  const ushort_t* wi3 = Wih + ((long)(3 * 1150 + us * 16 + lrow)) * 1152 + lk;

  // ---- cell state in registers ----
  f32x4 cc = {};
  if (u < 1150) {
#pragma unroll
    for (int r = 0; r < 4; ++r) cc[r] = cin[(row0 + r) * 1150 + u];
  }
  __syncthreads();   // LDS staging visible

  const int s1 = l, s2 = 64 + (l & 7);

  // low-traffic flag wait (r10-proven): one snapshot + targeted re-polls
  auto waitarr = [&](unsigned* f, unsigned tt, bool exempt) {
    unsigned f1 = (exempt && s1 == us) ? tt :
        __hip_atomic_load(f + (s1 << 5), __ATOMIC_RELAXED, __HIP_MEMORY_SCOPE_AGENT);
    unsigned f2 = (exempt && s2 == us) ? tt :
        __hip_atomic_load(f + (s2 << 5), __ATOMIC_RELAXED, __HIP_MEMORY_SCOPE_AGENT);
    unsigned long long p1 = __ballot(f1 >= tt);
    unsigned long long p2 = __ballot(f2 >= tt);
    while ((p1 & p2) != ~0ull) {
      __builtin_amdgcn_s_sleep(8);
      if (!((p1 >> l) & 1))
        f1 = __hip_atomic_load(f + (s1 << 5), __ATOMIC_RELAXED, __HIP_MEMORY_SCOPE_AGENT);
      if (!((p2 >> l) & 1))
        f2 = __hip_atomic_load(f + (s2 << 5), __ATOMIC_RELAXED, __HIP_MEMORY_SCOPE_AGENT);
      p1 = __ballot(f1 >= tt);
      p2 = __ballot(f2 >= tt);
    }
  };

  for (int t = 0; t < 100; ++t) {
    // layer-0: prefetch this step's G values (in flight during the wait)
    ushort_t gvv[16];
    if (L == 0) {
      const ushort_t* gp = G0 + ((long)t * 64 + row0) * 4608 + usafe;
#pragma unroll
      for (int r = 0; r < 4; ++r)
#pragma unroll
        for (int g = 0; g < 4; ++g)
          gvv[r * 4 + g] = gp[(long)r * 4608 + g * 1150];
    }

    if (w == 0) {
      if (t > 0) waitarr(fown, (unsigned)t, true);        // own h_L[t]
      if (L > 0) waitarr(fprev, (unsigned)(t + 1), false); // x = hs_P[t+1]
    }
    if (t > 0 || L > 0) {
      __syncthreads();
      asm volatile("" ::: "memory");
    }

    const ushort_t* hp = hsL + (long)t * 73728 + (long)(w * 16 + lrow) * 1152 + lk;
    f32x4 a0 = {}, a1 = {}, a2 = {}, a3 = {};

    if (L == 0) {
#pragma unroll 4
      for (int i = 0; i < 36; ++i) {
        int kc = start + i; if (kc >= 36) kc -= 36;
        bf16x8 a = *(const bf16x8*)(hp + kc * 32);
        int pc8 = ((kc * 4 + hi) ^ x7) * 8;
        a0 = __builtin_amdgcn_mfma_f32_16x16x32_bf16(a, *(const bf16x8*)(Bg0 + pc8), a0, 0, 0, 0);
        a1 = __builtin_amdgcn_mfma_f32_16x16x32_bf16(a, *(const bf16x8*)(Bg1 + pc8), a1, 0, 0, 0);
        a2 = __builtin_amdgcn_mfma_f32_16x16x32_bf16(a, *(const bf16x8*)(Bg2 + pc8), a2, 0, 0, 0);
        a3 = __builtin_amdgcn_mfma_f32_16x16x32_bf16(a, *(const bf16x8*)(Bg3 + pc8), a3, 0, 0, 0);
      }
    } else {
      const ushort_t* xp = hsP + (long)(t + 1) * 73728 + (long)(w * 16 + lrow) * 1152 + lk;
#pragma unroll 2
      for (int i = 0; i < 36; ++i) {
        int kc = start + i; if (kc >= 36) kc -= 36;
        int koff = kc * 32;
        bf16x8 ah = *(const bf16x8*)(hp + koff);
        bf16x8 ax = *(const bf16x8*)(xp + koff);
        int pc8 = ((kc * 4 + hi) ^ x7) * 8;
        a0 = __builtin_amdgcn_mfma_f32_16x16x32_bf16(ah, *(const bf16x8*)(Bg0 + pc8), a0, 0, 0, 0);
        a1 = __builtin_amdgcn_mfma_f32_16x16x32_bf16(ah, *(const bf16x8*)(Bg1 + pc8), a1, 0, 0, 0);
        a2 = __builtin_amdgcn_mfma_f32_16x16x32_bf16(ah, *(const bf16x8*)(Bg2 + pc8), a2, 0, 0, 0);
        a3 = __builtin_amdgcn_mfma_f32_16x16x32_bf16(ah, *(const bf16x8*)(Bg3 + pc8), a3, 0, 0, 0);
        a0 = __builtin_amdgcn_mfma_f32_16x16x32_bf16(ax, *(const bf16x8*)(wi0 + koff), a0, 0, 0, 0);
        a1 = __builtin_amdgcn_mfma_f32_16x16x32_bf16(ax, *(const bf16x8*)(wi1 + koff), a1, 0, 0, 0);
        a2 = __builtin_amdgcn_mfma_f32_16x16x32_bf16(ax, *(const bf16x8*)(wi2 + koff), a2, 0, 0, 0);
        a3 = __builtin_amdgcn_mfma_f32_16x16x32_bf16(ax, *(const bf16x8*)(wi3 + koff), a3, 0, 0, 0);
      }
    }

    if (u < 1150) {
#pragma unroll
      for (int r = 0; r < 4; ++r) {
        float iv, fv, gg, ov;
        if (L == 0) {
          iv = a0[r] + b2f(gvv[r * 4 + 0]);
          fv = a1[r] + b2f(gvv[r * 4 + 1]);
          gg = a2[r] + b2f(gvv[r * 4 + 2]);
          ov = a3[r] + b2f(gvv[r * 4 + 3]);
        } else {
          iv = a0[r] + bias4[0];
          fv = a1[r] + bias4[1];
          gg = a2[r] + bias4[2];
          ov = a3[r] + bias4[3];
        }
        float cn = sigm(fv) * cc[r] + sigm(iv) * tanhfast(gg);
        cc[r] = cn;
        float hv = sigm(ov) * tanhfast(cn);
        store_short_wt(hsL + (long)(t + 1) * 73728 + (long)(row0 + r) * 1152 + u, f2b(hv));
      }
    }

    // publish h_L[t+1] (needed by own next step and by layer L+1)
    asm volatile("s_waitcnt vmcnt(0)" ::: "memory");
    __syncthreads();
    if (tid == 0) store_uint_wt(fown + (us << 5), (unsigned)(t + 1));
  }
}

// =====================================================================
// Fused causal attention for one (t,b): scores -> softmax -> PV. f32 math.
// =====================================================================
__global__ __launch_bounds__(256) void attn_kernel(
    const ushort_t* __restrict__ hs2,  // base at hs[1]: [100][64][1152] bf16
    ushort_t* __restrict__ outp)       // [6400][1152] bf16
{
  __shared__ float qf[1152];
  __shared__ float sc[104];
  __shared__ float sinv;
  const int rowi = blockIdx.x;  // t*64 + b
  const int t = rowi >> 6, b = rowi & 63;
  const int tid = threadIdx.x;
  const int w = tid >> 6, l = tid & 63;

  const ushort_t* q = hs2 + (long)rowi * 1152;
  for (int c = tid; c < 1150; c += 256) qf[c] = b2f(q[c]);
  __syncthreads();

  for (int s = w; s <= t; s += 4) {
    const ushort_t* k = hs2 + (long)(s * 64 + b) * 1152;
    float p = 0.f;
    for (int h = l; h < 1150; h += 64) p += qf[h] * b2f(k[h]);
    for (int off = 32; off; off >>= 1) p += __shfl_down(p, off);
    if (l == 0) sc[s] = p;
  }
  __syncthreads();

  if (w == 0) {
    float m = -1e30f;
    for (int s = l; s <= t; s += 64) m = fmaxf(m, sc[s]);
    for (int off = 32; off; off >>= 1) m = fmaxf(m, __shfl_down(m, off));
    m = __shfl(m, 0);
    float sum = 0.f;
    for (int s = l; s <= t; s += 64) { float e = __expf(sc[s] - m); sc[s] = e; sum += e; }
    for (int off = 32; off; off >>= 1) sum += __shfl_down(sum, off);
    if (l == 0) sinv = 1.f / sum;
  }
  __syncthreads();

  const float si = sinv;
  for (int h = tid; h < 1150; h += 256) {
    float a = 0.f;
    for (int s = 0; s <= t; s++) a += sc[s] * b2f(hs2[(long)(s * 64 + b) * 1152 + h]);
    outp[(long)rowi * 1152 + h] = f2b(a * si);
  }
  if (tid < 2) outp[(long)rowi * 1152 + 1150 + tid] = 0;  // zero K-pad for decoder
}

// ---------- f32 -> bf16 conversion helpers ----------
__global__ void embed_kernel(const int* __restrict__ in1, const int* __restrict__ in2,
                             const float* __restrict__ emb, ushort_t* __restrict__ x0)
{
  int rowi = blockIdx.x;
  int l = threadIdx.x;    // 64 threads
  long r1 = (long)in1[rowi] * 400, r2 = (long)in2[rowi] * 400;
  ushort_t* d = x0 + (long)rowi * 800;
  for (int c = l; c < 800; c += 64)
    d[c] = f2b(c < 400 ? emb[r1 + c] : emb[r2 + c - 400]);
}

__global__ void pad_convert(const float* __restrict__ in, ushort_t* __restrict__ out,
                            int R, int Cin, int total, int Cp)
{
  int idx = blockIdx.x * 256 + threadIdx.x;
  if (idx >= total) return;
  int r = idx / Cp, c = idx - r * Cp;
  float v = (r < R && c < Cin) ? in[(long)r * Cin + c] : 0.f;
  out[idx] = f2b(v);
}

// init all 3 layers: hs[0], pad cols, flags. grid = dim3(288, 3)
__global__ void init_state3(const float* __restrict__ h0, const float* __restrict__ h1,
                            const float* __restrict__ h2,
                            ushort_t* __restrict__ hs0, ushort_t* __restrict__ hs1,
                            ushort_t* __restrict__ hs2,
                            unsigned* __restrict__ flags)
{
  int L = blockIdx.y;
  const float* h_in = (L == 0) ? h0 : (L == 1) ? h1 : h2;
  ushort_t* hs = (L == 0) ? hs0 : (L == 1) ? hs1 : hs2;
  int idx = blockIdx.x * 256 + threadIdx.x;
  if (idx < 72 * 32) flags[L * 2304 + idx] = 0u;
  if (idx < 64 * 1152) {
    int b = idx / 1152, c = idx - b * 1152;
    hs[idx] = (c < 1150) ? f2b(h_in[b * 1150 + c]) : (ushort_t)0;
  }
  if (idx < 100 * 128) {
    int t = idx >> 7, r = idx & 127, b = r >> 1, k = r & 1;
    hs[(long)(t + 1) * 73728 + b * 1152 + 1150 + k] = 0;
  }
}

// =====================================================================
extern "C" void kernel_launch(void* const* d_in, const int* in_sizes, int n_in,
                              void* d_out, int out_size, void* d_ws, size_t ws_size,
                              hipStream_t stream) {
  (void)in_sizes; (void)n_in; (void)out_size; (void)ws_size;
  const int* input  = (const int*)d_in[0];
  const int* input2 = (const int*)d_in[1];
  const float* h_in[3] = {(const float*)d_in[2], (const float*)d_in[4], (const float*)d_in[6]};
  const float* c_in[3] = {(const float*)d_in[3], (const float*)d_in[5], (const float*)d_in[7]};
  const float* emb_W = (const float*)d_in[8];
  const float* W_ih[3] = {(const float*)d_in[9],  (const float*)d_in[13], (const float*)d_in[17]};
  const float* W_hh[3] = {(const float*)d_in[10], (const float*)d_in[14], (const float*)d_in[18]};
  const float* b_ih[3] = {(const float*)d_in[11], (const float*)d_in[15], (const float*)d_in[19]};
  const float* b_hh[3] = {(const float*)d_in[12], (const float*)d_in[16], (const float*)d_in[20]};
  const float* dec_W = (const float*)d_in[21];
  const float* dec_b = (const float*)d_in[22];
  float* out = (float*)d_out;

  hipFuncSetAttribute((const void*)lstm_fused3,
                      hipFuncAttributeMaxDynamicSharedMemorySize, 147456);

  // ---- workspace: decoder-phase buffers + flags ----
  char* base = (char*)d_ws;
  size_t off = 0;
  auto walloc = [&](size_t bytes) { char* r = base + off; off += (bytes + 255) & ~(size_t)255; return r; };
  ushort_t* decWp = (ushort_t*)walloc(33280ull * 1152 * 2);   // 76,677,120
  ushort_t* attnB = (ushort_t*)walloc(6400ull * 1152 * 2);    // 14,745,600
  unsigned* flags = (unsigned*)walloc(3 * 72 * 128 + 256);

  // ---- layer-phase scratch inside d_out (852 MB f32; uses first ~175 MB,
  //      all dead before the decoder GEMM which reads only ws). ----
  char* ob = (char*)d_out;
  ushort_t* G0   = (ushort_t*)(ob + 0);            //  58,982,400
  ushort_t* x0   = (ushort_t*)(ob + 58982400);     //  10,240,000
  ushort_t* Wp0  = (ushort_t*)(ob + 69222400);     //   7,372,800 (4608x800)
  ushort_t* Whp0 = (ushort_t*)(ob + 76595200);     //  10,616,832
  ushort_t* Whp1 = (ushort_t*)(ob + 87212032);     //  10,616,832
  ushort_t* Whp2 = (ushort_t*)(ob + 97828864);     //  10,616,832
  ushort_t* Wip1 = (ushort_t*)(ob + 108445696);    //  10,616,832
  ushort_t* Wip2 = (ushort_t*)(ob + 119062528);    //  10,616,832
  ushort_t* hsL0 = (ushort_t*)(ob + 129679360);    //  14,893,056
  ushort_t* hsL1 = (ushort_t*)(ob + 144572416);    //  14,893,056
  ushort_t* hsL2 = (ushort_t*)(ob + 159465472);    //  -> end 174,358,528

  // ---- embedding ----
  embed_kernel<<<6400, 64, 0, stream>>>(input, input2, emb_W, x0);

  // ---- weight pads ----
  {
    int tot = 4608 * 800;
    pad_convert<<<(tot + 255) / 256, 256, 0, stream>>>(W_ih[0], Wp0, 4600, 800, tot, 800);
  }
  {
    int tot = 4608 * 1152;
    pad_convert<<<(tot + 255) / 256, 256, 0, stream>>>(W_hh[0], Whp0, 4600, 1150, tot, 1152);
    pad_convert<<<(tot + 255) / 256, 256, 0, stream>>>(W_hh[1], Whp1, 4600, 1150, tot, 1152);
    pad_convert<<<(tot + 255) / 256, 256, 0, stream>>>(W_hh[2], Whp2, 4600, 1150, tot, 1152);
    pad_convert<<<(tot + 255) / 256, 256, 0, stream>>>(W_ih[1], Wip1, 4600, 1150, tot, 1152);
    pad_convert<<<(tot + 255) / 256, 256, 0, stream>>>(W_ih[2], Wip2, 4600, 1150, tot, 1152);
  }

  // ---- layer-0 input GEMM: G0 = x0 @ Wih0^T + b_ih0 + b_hh0 (bf16) ----
  gemm_bt<false><<<dim3(25, 18), 512, 0, stream>>>(x0, Wp0, (void*)G0, b_ih[0], b_hh[0],
                                                   800, 800, 4608L, 800, 4600);

  // ---- init states + flags for all 3 layers ----
  init_state3<<<dim3(288, 3), 256, 0, stream>>>(h_in[0], h_in[1], h_in[2],
                                                hsL0, hsL1, hsL2, flags);

  // ---- fused pipelined 3-layer LSTM (216 blocks, all co-resident) ----
  lstm_fused3<<<216, 256, 147456, stream>>>(
      hsL0, hsL1, hsL2, G0, Whp0, Whp1, Whp2, Wip1, Wip2,
      c_in[0], c_in[1], c_in[2], b_ih[1], b_hh[1], b_ih[2], b_hh[2], flags);

  // ---- causal attention on layer-2 hidden states ----
  attn_kernel<<<6400, 256, 0, stream>>>(hsL2 + 73728, attnB);

  // ---- pad+convert decoder weight into ws ----
  {
    int tot = 33280 * 1152;
    pad_convert<<<(tot + 255) / 256, 256, 0, stream>>>(dec_W, decWp, 33278, 1150, tot, 1152);
  }

  // ---- decoder GEMM -> d_out (f32; reads only ws; overwrites all scratch) ----
  gemm_bt<true><<<dim3(25, 130), 512, 0, stream>>>(attnB, decWp, (void*)out, dec_b, nullptr,
                                                   1152, 1152, 33278L, 1152, 33278);
}

// Round 14
// 3680.862 us; speedup vs baseline: 1.1719x; 1.1719x over previous
//
#include <hip/hip_runtime.h>
#include <stdint.h>

typedef unsigned short ushort_t;
typedef __bf16 bf16x8 __attribute__((ext_vector_type(8)));
typedef float f32x4 __attribute__((ext_vector_type(4)));

// ---------- bf16 <-> f32 (bit ops) ----------
__device__ __forceinline__ float b2f(ushort_t u) {
  union { unsigned u; float f; } v; v.u = ((unsigned)u) << 16; return v.f;
}
__device__ __forceinline__ ushort_t f2b(float f) {
  union { float f; unsigned u; } v; v.f = f;
  unsigned r = (v.u + 0x7FFFu + ((v.u >> 16) & 1u)) >> 16;
  return (ushort_t)r;
}

// ---------- fast transcendentals (HW v_exp_f32 based) ----------
__device__ __forceinline__ float sigm(float x)     { return 1.f / (1.f + __expf(-x)); }
__device__ __forceinline__ float tanhfast(float x) { return 1.f - 2.f / (1.f + __expf(2.f * x)); }

// ---------- device-coherent write-through stores (visible at MALL) ----------
__device__ __forceinline__ void store_short_wt(ushort_t* p, ushort_t v) {
  asm volatile("global_store_short %0, %1, off sc0 sc1"
               :: "v"(p), "v"((unsigned)v) : "memory");
}
__device__ __forceinline__ void store_uint_wt(unsigned* p, unsigned v) {
  asm volatile("global_store_dword %0, %1, off sc0 sc1"
               :: "v"(p), "v"(v) : "memory");
}

// ---------- global -> LDS direct load, 16B per lane ----------
__device__ __forceinline__ void gload_lds16(const void* g, void* lds) {
  auto l3 = reinterpret_cast<__attribute__((address_space(3))) unsigned*>(
      reinterpret_cast<uintptr_t>(lds));
  __builtin_amdgcn_global_load_lds(reinterpret_cast<const unsigned*>(g), l3, 16, 0, 0);
}

// =====================================================================
// 256x256-tile GEMM (r12-proven): C = A@B^T + bias0 + bias1.
// =====================================================================
template <bool F32OUT>
__global__ __launch_bounds__(512) void gemm_bt(
    const ushort_t* __restrict__ A, const ushort_t* __restrict__ B,
    void* __restrict__ Cv,
    const float* __restrict__ bias0, const float* __restrict__ bias1,
    int lda, int ldb, long ldc, int Kpad, int N)
{
  __shared__ alignas(16) ushort_t As[256 * 32];
  __shared__ alignas(16) ushort_t Bs[256 * 32];
  const int tid = threadIdx.x;
  const int w = tid >> 6, l = tid & 63;
  const int wr = w >> 2, wc = w & 3;

  unsigned nwg = gridDim.x * gridDim.y;
  unsigned wg = blockIdx.y * gridDim.x + blockIdx.x;
  {
    unsigned q = nwg >> 3, r = nwg & 7u;
    unsigned xcd = wg & 7u, idx = wg >> 3;
    wg = (xcd < r ? xcd * (q + 1) : r * (q + 1) + (xcd - r) * q) + idx;
  }
  const long m0 = (long)(wg % gridDim.x) * 256;
  const long n0 = (long)(wg / gridDim.x) * 256;

  const int lrow = l & 15, hi = l >> 4, lk = hi * 8;

  f32x4 acc[8][4] = {};

  const int c0 = tid, c1 = tid + 512;
  const int r0 = c0 >> 2, g0 = (c0 & 3) * 8;
  const int r1 = c1 >> 2, g1 = (c1 & 3) * 8;

  for (int k0 = 0; k0 < Kpad; k0 += 32) {
    gload_lds16(A + (m0 + r0) * lda + k0 + g0, As + c0 * 8);
    gload_lds16(A + (m0 + r1) * lda + k0 + g1, As + c1 * 8);
    gload_lds16(B + (n0 + r0) * ldb + k0 + g0, Bs + c0 * 8);
    gload_lds16(B + (n0 + r1) * ldb + k0 + g1, Bs + c1 * 8);
    __syncthreads();

    bf16x8 af[8], bfr[4];
#pragma unroll
    for (int mi = 0; mi < 8; mi++)
      af[mi] = *(const bf16x8*)(As + (wr * 128 + mi * 16 + lrow) * 32 + lk);
#pragma unroll
    for (int ni = 0; ni < 4; ni++)
      bfr[ni] = *(const bf16x8*)(Bs + (wc * 64 + ni * 16 + lrow) * 32 + lk);
#pragma unroll
    for (int mi = 0; mi < 8; mi++)
#pragma unroll
      for (int ni = 0; ni < 4; ni++)
        acc[mi][ni] = __builtin_amdgcn_mfma_f32_16x16x32_bf16(af[mi], bfr[ni], acc[mi][ni], 0, 0, 0);
    __syncthreads();
  }

  const int rbase = hi * 4;
#pragma unroll
  for (int ni = 0; ni < 4; ni++) {
    int gcol = (int)n0 + wc * 64 + ni * 16 + lrow;
    if (gcol < N) {
      float badd = 0.f;
      if (bias0) badd += bias0[gcol];
      if (bias1) badd += bias1[gcol];
#pragma unroll
      for (int mi = 0; mi < 8; mi++) {
#pragma unroll
        for (int r = 0; r < 4; r++) {
          long grow = m0 + wr * 128 + mi * 16 + rbase + r;
          float v = acc[mi][ni][r] + badd;
          if (F32OUT) ((float*)Cv)[grow * ldc + gcol] = v;
          else        ((ushort_t*)Cv)[grow * ldc + gcol] = f2b(v);
        }
      }
    }
  }
}

// =====================================================================
// Persistent LSTM layer (r10/r12 transport + DEEP h-load pipeline):
// 72 blocks x 256 thr. The 36 h-chunks are loaded in 4 groups of 9 with
// two register groups in flight (issue g+2 while consuming g) -> DRAM
// latency exposure drops from ~9 serialized round trips to ~2-3.
// Whh slice in 144KB LDS (chunk-XOR swizzle); cell in regs; h via
// write-through stores; per-slice flags, low-traffic snapshot polling.
// =====================================================================
__global__ __launch_bounds__(256) void lstm_layer(
    ushort_t* __restrict__ hs,        // [101][64][1152] bf16
    const ushort_t* __restrict__ G,   // [6400][4608] bf16 (x@Wih^T + biases)
    const ushort_t* __restrict__ Whh, // padded [4608][1152] bf16
    const float* __restrict__ c_in,   // [64][1150] f32 initial cell
    unsigned* __restrict__ flags)     // 72 lines of 128B, zeroed per layer
{
  extern __shared__ ushort_t Bsh[];   // 4*16*144 chunks of 16B = 147456 B
  const int tid = threadIdx.x;
  const int w = tid >> 6, l = tid & 63;
  const int us = blockIdx.x;              // unit slice [0,72)
  const int lrow = l & 15, hi = l >> 4, lk = hi * 8;
  const int u = us * 16 + lrow;
  const int usafe = (u < 1150) ? u : 0;
  const int row0 = w * 16 + hi * 4;
  const int x7 = lrow & 7;
  const int start = us >> 1;              // rotated chunk start

  for (int ci = tid; ci < 9216; ci += 256) {
    int gate = ci / 2304;
    int rem  = ci - gate * 2304;
    int row  = rem / 144;
    int c    = rem - row * 144;
    bf16x8 v = *(const bf16x8*)(Whh + ((long)(gate * 1150 + us * 16 + row)) * 1152 + c * 8);
    *(bf16x8*)(Bsh + (((gate * 16 + row) * 144) + (c ^ (row & 7))) * 8) = v;
  }
  const ushort_t* Bg0 = Bsh + ((0 * 16 + lrow) * 144) * 8;
  const ushort_t* Bg1 = Bsh + ((1 * 16 + lrow) * 144) * 8;
  const ushort_t* Bg2 = Bsh + ((2 * 16 + lrow) * 144) * 8;
  const ushort_t* Bg3 = Bsh + ((3 * 16 + lrow) * 144) * 8;

  f32x4 cc = {};
  if (u < 1150) {
#pragma unroll
    for (int r = 0; r < 4; ++r) cc[r] = c_in[(row0 + r) * 1150 + u];
  }
  __syncthreads();

  const int s1 = l, s2 = 64 + (l & 7);

  for (int t = 0; t < 100; ++t) {
    // G prefetch for this step (independent of flags; in flight during wait)
    ushort_t gvv[16];
    {
      const ushort_t* gp = G + ((long)t * 64 + row0) * 4608 + usafe;
#pragma unroll
      for (int r = 0; r < 4; ++r)
#pragma unroll
        for (int g = 0; g < 4; ++g)
          gvv[r * 4 + g] = gp[(long)r * 4608 + g * 1150];
    }

    if (t > 0) {
      if (w == 0) {
        const unsigned tt = (unsigned)t;
        unsigned f1 = (s1 == us) ? tt :
            __hip_atomic_load(flags + (s1 << 5), __ATOMIC_RELAXED, __HIP_MEMORY_SCOPE_AGENT);
        unsigned f2 = (s2 == us) ? tt :
            __hip_atomic_load(flags + (s2 << 5), __ATOMIC_RELAXED, __HIP_MEMORY_SCOPE_AGENT);
        unsigned long long p1 = __ballot(f1 >= tt);
        unsigned long long p2 = __ballot(f2 >= tt);
        while ((p1 & p2) != ~0ull) {
          __builtin_amdgcn_s_sleep(8);
          if (!((p1 >> l) & 1))
            f1 = __hip_atomic_load(flags + (s1 << 5), __ATOMIC_RELAXED, __HIP_MEMORY_SCOPE_AGENT);
          if (!((p2 >> l) & 1))
            f2 = __hip_atomic_load(flags + (s2 << 5), __ATOMIC_RELAXED, __HIP_MEMORY_SCOPE_AGENT);
          p1 = __ballot(f1 >= tt);
          p2 = __ballot(f2 >= tt);
        }
      }
      __syncthreads();
      asm volatile("" ::: "memory");
    }

    const ushort_t* hp = hs + (long)t * 73728 + (long)(w * 16 + lrow) * 1152 + lk;
    f32x4 a0 = {}, a1 = {}, a2 = {}, a3 = {};

    // deep-pipelined h consumption: 4 groups of 9 chunks, 2 groups in flight
    bf16x8 A0[9], A1[9];
    auto ldg = [&](bf16x8* buf, int g) {
#pragma unroll
      for (int i = 0; i < 9; ++i) {
        int kc = start + g * 9 + i; if (kc >= 36) kc -= 36;
        buf[i] = *(const bf16x8*)(hp + kc * 32);
      }
    };
    auto cons = [&](const bf16x8* buf, int g) {
#pragma unroll
      for (int i = 0; i < 9; ++i) {
        int kc = start + g * 9 + i; if (kc >= 36) kc -= 36;
        int pc8 = ((kc * 4 + hi) ^ x7) * 8;
        a0 = __builtin_amdgcn_mfma_f32_16x16x32_bf16(buf[i], *(const bf16x8*)(Bg0 + pc8), a0, 0, 0, 0);
        a1 = __builtin_amdgcn_mfma_f32_16x16x32_bf16(buf[i], *(const bf16x8*)(Bg1 + pc8), a1, 0, 0, 0);
        a2 = __builtin_amdgcn_mfma_f32_16x16x32_bf16(buf[i], *(const bf16x8*)(Bg2 + pc8), a2, 0, 0, 0);
        a3 = __builtin_amdgcn_mfma_f32_16x16x32_bf16(buf[i], *(const bf16x8*)(Bg3 + pc8), a3, 0, 0, 0);
      }
    };
    ldg(A0, 0); ldg(A1, 1);     // groups 0,1 in flight
    cons(A0, 0); ldg(A0, 2);    // consume 0, issue 2
    cons(A1, 1); ldg(A1, 3);    // consume 1, issue 3
    cons(A0, 2);
    cons(A1, 3);

    if (u < 1150) {
#pragma unroll
      for (int r = 0; r < 4; ++r) {
        float iv = a0[r] + b2f(gvv[r * 4 + 0]);
        float fv = a1[r] + b2f(gvv[r * 4 + 1]);
        float gg = a2[r] + b2f(gvv[r * 4 + 2]);
        float ov = a3[r] + b2f(gvv[r * 4 + 3]);
        float cn = sigm(fv) * cc[r] + sigm(iv) * tanhfast(gg);
        cc[r] = cn;
        float hv = sigm(ov) * tanhfast(cn);
        store_short_wt(hs + (long)(t + 1) * 73728 + (long)(row0 + r) * 1152 + u, f2b(hv));
      }
    }

    if (t != 99) {
      asm volatile("s_waitcnt vmcnt(0)" ::: "memory");
      __syncthreads();
      if (tid == 0) store_uint_wt(flags + (us << 5), (unsigned)(t + 1));
    }
  }
}

// =====================================================================
// Fused causal attention for one (t,b): scores -> softmax -> PV. f32 math.
// =====================================================================
__global__ __launch_bounds__(256) void attn_kernel(
    const ushort_t* __restrict__ hs2,  // base at hs[1]: [100][64][1152] bf16
    ushort_t* __restrict__ outp)       // [6400][1152] bf16
{
  __shared__ float qf[1152];
  __shared__ float sc[104];
  __shared__ float sinv;
  const int rowi = blockIdx.x;  // t*64 + b
  const int t = rowi >> 6, b = rowi & 63;
  const int tid = threadIdx.x;
  const int w = tid >> 6, l = tid & 63;

  const ushort_t* q = hs2 + (long)rowi * 1152;
  for (int c = tid; c < 1150; c += 256) qf[c] = b2f(q[c]);
  __syncthreads();

  for (int s = w; s <= t; s += 4) {
    const ushort_t* k = hs2 + (long)(s * 64 + b) * 1152;
    float p = 0.f;
    for (int h = l; h < 1150; h += 64) p += qf[h] * b2f(k[h]);
    for (int off = 32; off; off >>= 1) p += __shfl_down(p, off);
    if (l == 0) sc[s] = p;
  }
  __syncthreads();

  if (w == 0) {
    float m = -1e30f;
    for (int s = l; s <= t; s += 64) m = fmaxf(m, sc[s]);
    for (int off = 32; off; off >>= 1) m = fmaxf(m, __shfl_down(m, off));
    m = __shfl(m, 0);
    float sum = 0.f;
    for (int s = l; s <= t; s += 64) { float e = __expf(sc[s] - m); sc[s] = e; sum += e; }
    for (int off = 32; off; off >>= 1) sum += __shfl_down(sum, off);
    if (l == 0) sinv = 1.f / sum;
  }
  __syncthreads();

  const float si = sinv;
  for (int h = tid; h < 1150; h += 256) {
    float a = 0.f;
    for (int s = 0; s <= t; s++) a += sc[s] * b2f(hs2[(long)(s * 64 + b) * 1152 + h]);
    outp[(long)rowi * 1152 + h] = f2b(a * si);
  }
  if (tid < 2) outp[(long)rowi * 1152 + 1150 + tid] = 0;  // zero K-pad for decoder
}

// ---------- f32 -> bf16 conversion helpers ----------
__global__ void embed_kernel(const int* __restrict__ in1, const int* __restrict__ in2,
                             const float* __restrict__ emb, ushort_t* __restrict__ x0)
{
  int rowi = blockIdx.x;
  int l = threadIdx.x;    // 64 threads
  long r1 = (long)in1[rowi] * 400, r2 = (long)in2[rowi] * 400;
  ushort_t* d = x0 + (long)rowi * 800;
  for (int c = l; c < 800; c += 64)
    d[c] = f2b(c < 400 ? emb[r1 + c] : emb[r2 + c - 400]);
}

__global__ void pad_convert(const float* __restrict__ in, ushort_t* __restrict__ out,
                            int R, int Cin, int total, int Cp)
{
  int idx = blockIdx.x * 256 + threadIdx.x;
  if (idx >= total) return;
  int r = idx / Cp, c = idx - r * Cp;
  float v = (r < R && c < Cin) ? in[(long)r * Cin + c] : 0.f;
  out[idx] = f2b(v);
}

__global__ void init_state(const float* __restrict__ h_in,
                           ushort_t* __restrict__ hs, unsigned* __restrict__ flags)
{
  int idx = blockIdx.x * 256 + threadIdx.x;  // grid covers 64*1152 = 73728
  if (idx < 72 * 32) flags[idx] = 0u;        // reset producer flags for this layer
  if (idx < 64 * 1152) {
    int b = idx / 1152, c = idx - b * 1152;
    hs[idx] = (c < 1150) ? f2b(h_in[b * 1150 + c]) : (ushort_t)0;
  }
  if (idx < 100 * 128) {  // zero K-pad cols of hs rows 1..100
    int t = idx >> 7, r = idx & 127, b = r >> 1, k = r & 1;
    hs[(long)(t + 1) * 73728 + b * 1152 + 1150 + k] = 0;
  }
}

// =====================================================================
extern "C" void kernel_launch(void* const* d_in, const int* in_sizes, int n_in,
                              void* d_out, int out_size, void* d_ws, size_t ws_size,
                              hipStream_t stream) {
  (void)in_sizes; (void)n_in; (void)out_size; (void)ws_size;
  const int* input  = (const int*)d_in[0];
  const int* input2 = (const int*)d_in[1];
  const float* h_in[3] = {(const float*)d_in[2], (const float*)d_in[4], (const float*)d_in[6]};
  const float* c_in[3] = {(const float*)d_in[3], (const float*)d_in[5], (const float*)d_in[7]};
  const float* emb_W = (const float*)d_in[8];
  const float* W_ih[3] = {(const float*)d_in[9],  (const float*)d_in[13], (const float*)d_in[17]};
  const float* W_hh[3] = {(const float*)d_in[10], (const float*)d_in[14], (const float*)d_in[18]};
  const float* b_ih[3] = {(const float*)d_in[11], (const float*)d_in[15], (const float*)d_in[19]};
  const float* b_hh[3] = {(const float*)d_in[12], (const float*)d_in[16], (const float*)d_in[20]};
  const float* dec_W = (const float*)d_in[21];
  const float* dec_b = (const float*)d_in[22];
  float* out = (float*)d_out;

  // allow 144KB dynamic LDS for the persistent LSTM kernel
  hipFuncSetAttribute((const void*)lstm_layer,
                      hipFuncAttributeMaxDynamicSharedMemorySize, 147456);

  // ---- workspace: buffers alive during the final decoder GEMM + flags ----
  char* base = (char*)d_ws;
  size_t off = 0;
  auto walloc = [&](size_t bytes) { char* r = base + off; off += (bytes + 255) & ~(size_t)255; return r; };
  ushort_t* decWp = (ushort_t*)walloc(33280ull * 1152 * 2);   // 76,677,120
  ushort_t* attnB = (ushort_t*)walloc(6400ull * 1152 * 2);    // 14,745,600
  unsigned* flags = (unsigned*)walloc(72 * 128 + 256);

  // ---- layer-phase scratch inside d_out (852 MB f32; scratch uses first
  //      ~120 MB, all dead before the decoder GEMM which reads only ws). ----
  char* ob = (char*)d_out;
  ushort_t* G   = (ushort_t*)(ob + 0);            // 58,982,400
  ushort_t* x0  = (ushort_t*)(ob + 58982400);     // 10,240,000
  ushort_t* Wp  = (ushort_t*)(ob + 69222400);     // 10,616,832
  ushort_t* Whp = (ushort_t*)(ob + 79839232);     // 10,616,832
  ushort_t* hsA = (ushort_t*)(ob + 90456064);     // 14,893,056
  ushort_t* hsB = (ushort_t*)(ob + 105349120);    // -> end 120,242,176

  embed_kernel<<<6400, 64, 0, stream>>>(input, input2, emb_W, x0);

  ushort_t* hcur[3] = {hsA, hsB, hsA};
  const ushort_t* X = x0;
  int lda = 800, Kp = 800;
  for (int lyr = 0; lyr < 3; lyr++) {
    if (lyr == 0) {
      int tot = 4608 * 800;
      pad_convert<<<(tot + 255) / 256, 256, 0, stream>>>(W_ih[0], Wp, 4600, 800, tot, 800);
    } else {
      int tot = 4608 * 1152;
      pad_convert<<<(tot + 255) / 256, 256, 0, stream>>>(W_ih[lyr], Wp, 4600, 1150, tot, 1152);
    }
    {
      int tot = 4608 * 1152;
      pad_convert<<<(tot + 255) / 256, 256, 0, stream>>>(W_hh[lyr], Whp, 4600, 1150, tot, 1152);
    }
    // G = X @ Wih^T + b_ih + b_hh  (bf16 out; 256^2 tile, 18*256=4608 cols)
    gemm_bt<false><<<dim3(25, 18), 512, 0, stream>>>(X, Wp, (void*)G, b_ih[lyr], b_hh[lyr],
                                                     lda, Kp, 4608L, Kp, 4600);
    init_state<<<288, 256, 0, stream>>>(h_in[lyr], hcur[lyr], flags);
    lstm_layer<<<72, 256, 147456, stream>>>(hcur[lyr], G, Whp, c_in[lyr], flags);
    X = hcur[lyr] + 73728;
    lda = 1152; Kp = 1152;
  }

  attn_kernel<<<6400, 256, 0, stream>>>(hsA + 73728, attnB);

  {
    int tot = 33280 * 1152;
    pad_convert<<<(tot + 255) / 256, 256, 0, stream>>>(dec_W, decWp, 33278, 1150, tot, 1152);
  }

  // decoder GEMM -> d_out (f32 out; reads only ws; overwrites all scratch)
  gemm_bt<true><<<dim3(25, 130), 512, 0, stream>>>(attnB, decWp, (void*)out, dec_b, nullptr,
                                                   1152, 1152, 33278L, 1152, 33278);
}

// Round 15
// 3355.147 us; speedup vs baseline: 1.2857x; 1.0971x over previous
//
#include <hip/hip_runtime.h>
#include <stdint.h>

typedef unsigned short ushort_t;
typedef __bf16 bf16x8 __attribute__((ext_vector_type(8)));
typedef float f32x4 __attribute__((ext_vector_type(4)));

// ---------- bf16 <-> f32 (bit ops) ----------
__device__ __forceinline__ float b2f(ushort_t u) {
  union { unsigned u; float f; } v; v.u = ((unsigned)u) << 16; return v.f;
}
__device__ __forceinline__ ushort_t f2b(float f) {
  union { float f; unsigned u; } v; v.f = f;
  unsigned r = (v.u + 0x7FFFu + ((v.u >> 16) & 1u)) >> 16;
  return (ushort_t)r;
}

// ---------- fast transcendentals ----------
__device__ __forceinline__ float sigm(float x)     { return 1.f / (1.f + __expf(-x)); }
__device__ __forceinline__ float tanhfast(float x) { return 1.f - 2.f / (1.f + __expf(2.f * x)); }

// ---------- device-coherent write-through stores ----------
__device__ __forceinline__ void store_short_wt(ushort_t* p, ushort_t v) {
  asm volatile("global_store_short %0, %1, off sc0 sc1"
               :: "v"(p), "v"((unsigned)v) : "memory");
}
__device__ __forceinline__ void store_uint_wt(unsigned* p, unsigned v) {
  asm volatile("global_store_dword %0, %1, off sc0 sc1"
               :: "v"(p), "v"(v) : "memory");
}

// ---------- global -> LDS direct load, 16B per lane ----------
__device__ __forceinline__ void gload_lds16(const void* g, void* lds) {
  auto l3 = reinterpret_cast<__attribute__((address_space(3))) unsigned*>(
      reinterpret_cast<uintptr_t>(lds));
  __builtin_amdgcn_global_load_lds(reinterpret_cast<const unsigned*>(g), l3, 16, 0, 0);
}

// raw barrier with compiler memory fences (no vmcnt(0) drain)
__device__ __forceinline__ void rbar() {
  asm volatile("" ::: "memory");
  __builtin_amdgcn_s_barrier();
  asm volatile("" ::: "memory");
}

// =====================================================================
// 256x256 pipelined GEMM: C = A@B^T + bias0 + bias1. bf16 in, f32 acc,
// f32/bf16 out. BK=64, double-buffered 128KB LDS, counted vmcnt(8)
// (tile t+1 in flight while computing t), raw s_barriers, T2 LDS swizzle
// (colE ^= (row&7)<<3, both sides), setprio around MFMA clusters.
// 512 thr = 8 waves (2Mx4N), wave tile 128x64, acc[8][4].
// Requires: M%256==0, B rows padded to gridDim.y*256, Kpad%64==0, nt>=2.
// =====================================================================
template <bool F32OUT>
__global__ __launch_bounds__(512) void gemm256(
    const ushort_t* __restrict__ A, const ushort_t* __restrict__ B,
    void* __restrict__ Cv,
    const float* __restrict__ bias0, const float* __restrict__ bias1,
    int lda, int ldb, long ldc, int Kpad, int N)
{
  extern __shared__ ushort_t sh[];   // [2 buf][A 16384 | B 16384] ushorts = 131072 B
  const int tid = threadIdx.x;
  const int w = tid >> 6, l = tid & 63;
  const int wr = w >> 2, wc = w & 3;
  const int lrow = l & 15, hi = l >> 4;
  const int xsw = (lrow & 7) << 3;     // element-unit swizzle for this lane's reads

  // bijective XCD swizzle
  unsigned nwg = gridDim.x * gridDim.y;
  unsigned wg = blockIdx.y * gridDim.x + blockIdx.x;
  {
    unsigned q = nwg >> 3, r = nwg & 7u;
    unsigned xcd = wg & 7u, idx = wg >> 3;
    wg = (xcd < r ? xcd * (q + 1) : r * (q + 1) + (xcd - r) * q) + idx;
  }
  const long m0 = (long)(wg % gridDim.x) * 256;
  const long n0 = (long)(wg / gridDim.x) * 256;

  // staging geometry: per tensor 2048 chunks of 8 ushorts; thread does 4.
  // chunk c -> LDS row c>>3, colE (c&7)*8 (linear dest); global source col
  // is inverse-swizzled so that swizzled reads see logical data.
  int crow[4], csrc[4];
#pragma unroll
  for (int j = 0; j < 4; ++j) {
    int c = tid + j * 512;
    crow[j] = c >> 3;
    csrc[j] = ((c & 7) * 8) ^ ((crow[j] & 7) << 3);
  }

  auto STAGE = [&](int buf, int t) {
    const long k0 = (long)t * 64;
    ushort_t* dstA = sh + buf * 32768;
    ushort_t* dstB = dstA + 16384;
#pragma unroll
    for (int j = 0; j < 4; ++j)
      gload_lds16(A + (m0 + crow[j]) * lda + k0 + csrc[j], dstA + (tid + j * 512) * 8);
#pragma unroll
    for (int j = 0; j < 4; ++j)
      gload_lds16(B + (n0 + crow[j]) * ldb + k0 + csrc[j], dstB + (tid + j * 512) * 8);
  };

  f32x4 acc[8][4] = {};
  const int nt = Kpad >> 6;

  STAGE(0, 0);
  STAGE(1, 1);
  asm volatile("s_waitcnt vmcnt(8)" ::: "memory");   // tile 0 landed (tile 1 flying)
  rbar();

  for (int t = 0; t < nt; ++t) {
    const ushort_t* As = sh + (t & 1) * 32768;
    const ushort_t* Bs = As + 16384;
#pragma unroll
    for (int kk = 0; kk < 2; ++kk) {
      bf16x8 af[8], bfr[4];
      const int co = (kk * 32 + hi * 8) ^ xsw;
#pragma unroll
      for (int mi = 0; mi < 8; ++mi)
        af[mi] = *(const bf16x8*)(As + (wr * 128 + mi * 16 + lrow) * 64 + co);
#pragma unroll
      for (int ni = 0; ni < 4; ++ni)
        bfr[ni] = *(const bf16x8*)(Bs + (wc * 64 + ni * 16 + lrow) * 64 + co);
      __builtin_amdgcn_s_setprio(1);
#pragma unroll
      for (int mi = 0; mi < 8; ++mi)
#pragma unroll
        for (int ni = 0; ni < 4; ++ni)
          acc[mi][ni] = __builtin_amdgcn_mfma_f32_16x16x32_bf16(af[mi], bfr[ni], acc[mi][ni], 0, 0, 0);
      __builtin_amdgcn_s_setprio(0);
    }
    if (t + 2 < nt) {
      rbar();                      // all waves done reading buf[t&1]
      STAGE(t & 1, t + 2);         // 8 loads into the freed buffer
      asm volatile("s_waitcnt vmcnt(8)" ::: "memory");  // tile t+1 (oldest 8) landed
      rbar();                      // tile t+1 visible to all waves
    } else if (t + 1 < nt) {
      rbar();
      asm volatile("s_waitcnt vmcnt(0)" ::: "memory");  // last tile landed
      rbar();
    }
  }

  // epilogue (r12-proven layout): lane -> col = lrow, rows = hi*4 + r
  const int rbase = hi * 4;
#pragma unroll
  for (int ni = 0; ni < 4; ni++) {
    int gcol = (int)n0 + wc * 64 + ni * 16 + lrow;
    if (gcol < N) {
      float badd = 0.f;
      if (bias0) badd += bias0[gcol];
      if (bias1) badd += bias1[gcol];
#pragma unroll
      for (int mi = 0; mi < 8; mi++) {
#pragma unroll
        for (int r = 0; r < 4; r++) {
          long grow = m0 + wr * 128 + mi * 16 + rbase + r;
          float v = acc[mi][ni][r] + badd;
          if (F32OUT) ((float*)Cv)[grow * ldc + gcol] = v;
          else        ((ushort_t*)Cv)[grow * ldc + gcol] = f2b(v);
        }
      }
    }
  }
}

// =====================================================================
// Persistent LSTM layer (r14 form: flags + deep h-load pipeline)
// =====================================================================
__global__ __launch_bounds__(256) void lstm_layer(
    ushort_t* __restrict__ hs,        // [101][64][1152] bf16
    const ushort_t* __restrict__ G,   // [6400][4608] bf16 (x@Wih^T + biases)
    const ushort_t* __restrict__ Whh, // padded [4608][1152] bf16
    const float* __restrict__ c_in,   // [64][1150] f32 initial cell
    unsigned* __restrict__ flags)     // 72 lines of 128B, zeroed per layer
{
  extern __shared__ ushort_t Bsh[];   // 4*16*144 chunks of 16B = 147456 B
  const int tid = threadIdx.x;
  const int w = tid >> 6, l = tid & 63;
  const int us = blockIdx.x;
  const int lrow = l & 15, hi = l >> 4, lk = hi * 8;
  const int u = us * 16 + lrow;
  const int usafe = (u < 1150) ? u : 0;
  const int row0 = w * 16 + hi * 4;
  const int x7 = lrow & 7;
  const int start = us >> 1;

  for (int ci = tid; ci < 9216; ci += 256) {
    int gate = ci / 2304;
    int rem  = ci - gate * 2304;
    int row  = rem / 144;
    int c    = rem - row * 144;
    bf16x8 v = *(const bf16x8*)(Whh + ((long)(gate * 1150 + us * 16 + row)) * 1152 + c * 8);
    *(bf16x8*)(Bsh + (((gate * 16 + row) * 144) + (c ^ (row & 7))) * 8) = v;
  }
  const ushort_t* Bg0 = Bsh + ((0 * 16 + lrow) * 144) * 8;
  const ushort_t* Bg1 = Bsh + ((1 * 16 + lrow) * 144) * 8;
  const ushort_t* Bg2 = Bsh + ((2 * 16 + lrow) * 144) * 8;
  const ushort_t* Bg3 = Bsh + ((3 * 16 + lrow) * 144) * 8;

  f32x4 cc = {};
  if (u < 1150) {
#pragma unroll
    for (int r = 0; r < 4; ++r) cc[r] = c_in[(row0 + r) * 1150 + u];
  }
  __syncthreads();

  const int s1 = l, s2 = 64 + (l & 7);

  for (int t = 0; t < 100; ++t) {
    ushort_t gvv[16];
    {
      const ushort_t* gp = G + ((long)t * 64 + row0) * 4608 + usafe;
#pragma unroll
      for (int r = 0; r < 4; ++r)
#pragma unroll
        for (int g = 0; g < 4; ++g)
          gvv[r * 4 + g] = gp[(long)r * 4608 + g * 1150];
    }

    if (t > 0) {
      if (w == 0) {
        const unsigned tt = (unsigned)t;
        unsigned f1 = (s1 == us) ? tt :
            __hip_atomic_load(flags + (s1 << 5), __ATOMIC_RELAXED, __HIP_MEMORY_SCOPE_AGENT);
        unsigned f2 = (s2 == us) ? tt :
            __hip_atomic_load(flags + (s2 << 5), __ATOMIC_RELAXED, __HIP_MEMORY_SCOPE_AGENT);
        unsigned long long p1 = __ballot(f1 >= tt);
        unsigned long long p2 = __ballot(f2 >= tt);
        while ((p1 & p2) != ~0ull) {
          __builtin_amdgcn_s_sleep(8);
          if (!((p1 >> l) & 1))
            f1 = __hip_atomic_load(flags + (s1 << 5), __ATOMIC_RELAXED, __HIP_MEMORY_SCOPE_AGENT);
          if (!((p2 >> l) & 1))
            f2 = __hip_atomic_load(flags + (s2 << 5), __ATOMIC_RELAXED, __HIP_MEMORY_SCOPE_AGENT);
          p1 = __ballot(f1 >= tt);
          p2 = __ballot(f2 >= tt);
        }
      }
      __syncthreads();
      asm volatile("" ::: "memory");
    }

    const ushort_t* hp = hs + (long)t * 73728 + (long)(w * 16 + lrow) * 1152 + lk;
    f32x4 a0 = {}, a1 = {}, a2 = {}, a3 = {};

    bf16x8 A0[9], A1[9];
    auto ldg = [&](bf16x8* buf, int g) {
#pragma unroll
      for (int i = 0; i < 9; ++i) {
        int kc = start + g * 9 + i; if (kc >= 36) kc -= 36;
        buf[i] = *(const bf16x8*)(hp + kc * 32);
      }
    };
    auto cons = [&](const bf16x8* buf, int g) {
#pragma unroll
      for (int i = 0; i < 9; ++i) {
        int kc = start + g * 9 + i; if (kc >= 36) kc -= 36;
        int pc8 = ((kc * 4 + hi) ^ x7) * 8;
        a0 = __builtin_amdgcn_mfma_f32_16x16x32_bf16(buf[i], *(const bf16x8*)(Bg0 + pc8), a0, 0, 0, 0);
        a1 = __builtin_amdgcn_mfma_f32_16x16x32_bf16(buf[i], *(const bf16x8*)(Bg1 + pc8), a1, 0, 0, 0);
        a2 = __builtin_amdgcn_mfma_f32_16x16x32_bf16(buf[i], *(const bf16x8*)(Bg2 + pc8), a2, 0, 0, 0);
        a3 = __builtin_amdgcn_mfma_f32_16x16x32_bf16(buf[i], *(const bf16x8*)(Bg3 + pc8), a3, 0, 0, 0);
      }
    };
    ldg(A0, 0); ldg(A1, 1);
    cons(A0, 0); ldg(A0, 2);
    cons(A1, 1); ldg(A1, 3);
    cons(A0, 2);
    cons(A1, 3);

    if (u < 1150) {
#pragma unroll
      for (int r = 0; r < 4; ++r) {
        float iv = a0[r] + b2f(gvv[r * 4 + 0]);
        float fv = a1[r] + b2f(gvv[r * 4 + 1]);
        float gg = a2[r] + b2f(gvv[r * 4 + 2]);
        float ov = a3[r] + b2f(gvv[r * 4 + 3]);
        float cn = sigm(fv) * cc[r] + sigm(iv) * tanhfast(gg);
        cc[r] = cn;
        float hv = sigm(ov) * tanhfast(cn);
        store_short_wt(hs + (long)(t + 1) * 73728 + (long)(row0 + r) * 1152 + u, f2b(hv));
      }
    }

    if (t != 99) {
      asm volatile("s_waitcnt vmcnt(0)" ::: "memory");
      __syncthreads();
      if (tid == 0) store_uint_wt(flags + (us << 5), (unsigned)(t + 1));
    }
  }
}

// =====================================================================
// Fused causal attention for one (t,b): scores -> softmax -> PV. f32 math.
// =====================================================================
__global__ __launch_bounds__(256) void attn_kernel(
    const ushort_t* __restrict__ hs2,  // base at hs[1]: [100][64][1152] bf16
    ushort_t* __restrict__ outp)       // [6400][1152] bf16
{
  __shared__ float qf[1152];
  __shared__ float sc[104];
  __shared__ float sinv;
  const int rowi = blockIdx.x;  // t*64 + b
  const int t = rowi >> 6, b = rowi & 63;
  const int tid = threadIdx.x;
  const int w = tid >> 6, l = tid & 63;

  const ushort_t* q = hs2 + (long)rowi * 1152;
  for (int c = tid; c < 1150; c += 256) qf[c] = b2f(q[c]);
  __syncthreads();

  for (int s = w; s <= t; s += 4) {
    const ushort_t* k = hs2 + (long)(s * 64 + b) * 1152;
    float p = 0.f;
    for (int h = l; h < 1150; h += 64) p += qf[h] * b2f(k[h]);
    for (int off = 32; off; off >>= 1) p += __shfl_down(p, off);
    if (l == 0) sc[s] = p;
  }
  __syncthreads();

  if (w == 0) {
    float m = -1e30f;
    for (int s = l; s <= t; s += 64) m = fmaxf(m, sc[s]);
    for (int off = 32; off; off >>= 1) m = fmaxf(m, __shfl_down(m, off));
    m = __shfl(m, 0);
    float sum = 0.f;
    for (int s = l; s <= t; s += 64) { float e = __expf(sc[s] - m); sc[s] = e; sum += e; }
    for (int off = 32; off; off >>= 1) sum += __shfl_down(sum, off);
    if (l == 0) sinv = 1.f / sum;
  }
  __syncthreads();

  const float si = sinv;
  for (int h = tid; h < 1150; h += 256) {
    float a = 0.f;
    for (int s = 0; s <= t; s++) a += sc[s] * b2f(hs2[(long)(s * 64 + b) * 1152 + h]);
    outp[(long)rowi * 1152 + h] = f2b(a * si);
  }
  if (tid < 2) outp[(long)rowi * 1152 + 1150 + tid] = 0;  // zero K-pad for decoder
}

// ---------- f32 -> bf16 conversion helpers ----------
__global__ void embed_kernel(const int* __restrict__ in1, const int* __restrict__ in2,
                             const float* __restrict__ emb, ushort_t* __restrict__ x0)
{
  int rowi = blockIdx.x;
  int l = threadIdx.x;    // 64 threads
  long r1 = (long)in1[rowi] * 400, r2 = (long)in2[rowi] * 400;
  ushort_t* d = x0 + (long)rowi * 832;   // K padded 800 -> 832 (zeros)
  for (int c = l; c < 832; c += 64) {
    ushort_t v = 0;
    if (c < 800) v = f2b(c < 400 ? emb[r1 + c] : emb[r2 + c - 400]);
    d[c] = v;
  }
}

__global__ void pad_convert(const float* __restrict__ in, ushort_t* __restrict__ out,
                            int R, int Cin, int total, int Cp)
{
  int idx = blockIdx.x * 256 + threadIdx.x;
  if (idx >= total) return;
  int r = idx / Cp, c = idx - r * Cp;
  float v = (r < R && c < Cin) ? in[(long)r * Cin + c] : 0.f;
  out[idx] = f2b(v);
}

__global__ void init_state(const float* __restrict__ h_in,
                           ushort_t* __restrict__ hs, unsigned* __restrict__ flags)
{
  int idx = blockIdx.x * 256 + threadIdx.x;  // grid covers 64*1152 = 73728
  if (idx < 72 * 32) flags[idx] = 0u;
  if (idx < 64 * 1152) {
    int b = idx / 1152, c = idx - b * 1152;
    hs[idx] = (c < 1150) ? f2b(h_in[b * 1150 + c]) : (ushort_t)0;
  }
  if (idx < 100 * 128) {
    int t = idx >> 7, r = idx & 127, b = r >> 1, k = r & 1;
    hs[(long)(t + 1) * 73728 + b * 1152 + 1150 + k] = 0;
  }
}

// =====================================================================
extern "C" void kernel_launch(void* const* d_in, const int* in_sizes, int n_in,
                              void* d_out, int out_size, void* d_ws, size_t ws_size,
                              hipStream_t stream) {
  (void)in_sizes; (void)n_in; (void)out_size; (void)ws_size;
  const int* input  = (const int*)d_in[0];
  const int* input2 = (const int*)d_in[1];
  const float* h_in[3] = {(const float*)d_in[2], (const float*)d_in[4], (const float*)d_in[6]};
  const float* c_in[3] = {(const float*)d_in[3], (const float*)d_in[5], (const float*)d_in[7]};
  const float* emb_W = (const float*)d_in[8];
  const float* W_ih[3] = {(const float*)d_in[9],  (const float*)d_in[13], (const float*)d_in[17]};
  const float* W_hh[3] = {(const float*)d_in[10], (const float*)d_in[14], (const float*)d_in[18]};
  const float* b_ih[3] = {(const float*)d_in[11], (const float*)d_in[15], (const float*)d_in[19]};
  const float* b_hh[3] = {(const float*)d_in[12], (const float*)d_in[16], (const float*)d_in[20]};
  const float* dec_W = (const float*)d_in[21];
  const float* dec_b = (const float*)d_in[22];
  float* out = (float*)d_out;

  hipFuncSetAttribute((const void*)lstm_layer,
                      hipFuncAttributeMaxDynamicSharedMemorySize, 147456);
  hipFuncSetAttribute(reinterpret_cast<const void*>(gemm256<false>),
                      hipFuncAttributeMaxDynamicSharedMemorySize, 131072);
  hipFuncSetAttribute(reinterpret_cast<const void*>(gemm256<true>),
                      hipFuncAttributeMaxDynamicSharedMemorySize, 131072);

  // ---- workspace: decoder-phase buffers + flags ----
  char* base = (char*)d_ws;
  size_t off = 0;
  auto walloc = [&](size_t bytes) { char* r = base + off; off += (bytes + 255) & ~(size_t)255; return r; };
  ushort_t* decWp = (ushort_t*)walloc(33280ull * 1152 * 2);   // 76,677,120
  ushort_t* attnB = (ushort_t*)walloc(6400ull * 1152 * 2);    // 14,745,600
  unsigned* flags = (unsigned*)walloc(72 * 128 + 256);

  // ---- layer-phase scratch inside d_out (all dead before decoder GEMM) ----
  char* ob = (char*)d_out;
  ushort_t* G   = (ushort_t*)(ob + 0);            // 58,982,400
  ushort_t* x0  = (ushort_t*)(ob + 58982400);     // 6400*832*2 = 10,649,600
  ushort_t* Wp  = (ushort_t*)(ob + 69632000);     // 10,616,832 (max 4608x1152)
  ushort_t* Whp = (ushort_t*)(ob + 80248832);     // 10,616,832
  ushort_t* hsA = (ushort_t*)(ob + 90865664);     // 14,893,056
  ushort_t* hsB = (ushort_t*)(ob + 105758720);    // -> end 120,651,776

  embed_kernel<<<6400, 64, 0, stream>>>(input, input2, emb_W, x0);

  ushort_t* hcur[3] = {hsA, hsB, hsA};
  const ushort_t* X = x0;
  int lda = 832, Kp = 832;
  for (int lyr = 0; lyr < 3; lyr++) {
    if (lyr == 0) {
      int tot = 4608 * 832;
      pad_convert<<<(tot + 255) / 256, 256, 0, stream>>>(W_ih[0], Wp, 4600, 800, tot, 832);
    } else {
      int tot = 4608 * 1152;
      pad_convert<<<(tot + 255) / 256, 256, 0, stream>>>(W_ih[lyr], Wp, 4600, 1150, tot, 1152);
    }
    {
      int tot = 4608 * 1152;
      pad_convert<<<(tot + 255) / 256, 256, 0, stream>>>(W_hh[lyr], Whp, 4600, 1150, tot, 1152);
    }
    // G = X @ Wih^T + b_ih + b_hh  (bf16 out; 4608 = 18*256 cols)
    gemm256<false><<<dim3(25, 18), 512, 131072, stream>>>(X, Wp, (void*)G, b_ih[lyr], b_hh[lyr],
                                                          lda, Kp, 4608L, Kp, 4600);
    init_state<<<288, 256, 0, stream>>>(h_in[lyr], hcur[lyr], flags);
    lstm_layer<<<72, 256, 147456, stream>>>(hcur[lyr], G, Whp, c_in[lyr], flags);
    X = hcur[lyr] + 73728;
    lda = 1152; Kp = 1152;
  }

  attn_kernel<<<6400, 256, 0, stream>>>(hsA + 73728, attnB);

  {
    int tot = 33280 * 1152;
    pad_convert<<<(tot + 255) / 256, 256, 0, stream>>>(dec_W, decWp, 33278, 1150, tot, 1152);
  }

  // decoder GEMM -> d_out (f32; reads only ws; overwrites all scratch)
  gemm256<true><<<dim3(25, 130), 512, 131072, stream>>>(attnB, decWp, (void*)out, dec_b, nullptr,
                                                        1152, 1152, 33278L, 1152, 33278);
}

// Round 16
// 3236.118 us; speedup vs baseline: 1.3330x; 1.0368x over previous
//
#include <hip/hip_runtime.h>
#include <stdint.h>

typedef unsigned short ushort_t;
typedef __bf16 bf16x8 __attribute__((ext_vector_type(8)));
typedef ushort_t us8 __attribute__((ext_vector_type(8)));
typedef float f32x4 __attribute__((ext_vector_type(4)));

// ---------- bf16 <-> f32 (bit ops) ----------
__device__ __forceinline__ float b2f(ushort_t u) {
  union { unsigned u; float f; } v; v.u = ((unsigned)u) << 16; return v.f;
}
__device__ __forceinline__ ushort_t f2b(float f) {
  union { float f; unsigned u; } v; v.f = f;
  unsigned r = (v.u + 0x7FFFu + ((v.u >> 16) & 1u)) >> 16;
  return (ushort_t)r;
}

// ---------- fast transcendentals ----------
__device__ __forceinline__ float sigm(float x)     { return 1.f / (1.f + __expf(-x)); }
__device__ __forceinline__ float tanhfast(float x) { return 1.f - 2.f / (1.f + __expf(2.f * x)); }

// ---------- device-coherent write-through stores ----------
__device__ __forceinline__ void store_short_wt(ushort_t* p, ushort_t v) {
  asm volatile("global_store_short %0, %1, off sc0 sc1"
               :: "v"(p), "v"((unsigned)v) : "memory");
}
__device__ __forceinline__ void store_uint_wt(unsigned* p, unsigned v) {
  asm volatile("global_store_dword %0, %1, off sc0 sc1"
               :: "v"(p), "v"(v) : "memory");
}

// ---------- global -> LDS direct load, 16B per lane ----------
__device__ __forceinline__ void gload_lds16(const void* g, void* lds) {
  auto l3 = reinterpret_cast<__attribute__((address_space(3))) unsigned*>(
      reinterpret_cast<uintptr_t>(lds));
  __builtin_amdgcn_global_load_lds(reinterpret_cast<const unsigned*>(g), l3, 16, 0, 0);
}

// raw barrier with compiler memory fences (no vmcnt(0) drain)
__device__ __forceinline__ void rbar() {
  asm volatile("" ::: "memory");
  __builtin_amdgcn_s_barrier();
  asm volatile("" ::: "memory");
}

// =====================================================================
// 256x256 pipelined GEMM (r15-proven): BK=64, dbuf LDS, counted vmcnt(8),
// raw barriers, T2 swizzle both-sides, setprio. 512 thr (8 waves).
// =====================================================================
template <bool F32OUT>
__global__ __launch_bounds__(512) void gemm256(
    const ushort_t* __restrict__ A, const ushort_t* __restrict__ B,
    void* __restrict__ Cv,
    const float* __restrict__ bias0, const float* __restrict__ bias1,
    int lda, int ldb, long ldc, int Kpad, int N)
{
  extern __shared__ ushort_t sh[];
  const int tid = threadIdx.x;
  const int w = tid >> 6, l = tid & 63;
  const int wr = w >> 2, wc = w & 3;
  const int lrow = l & 15, hi = l >> 4;
  const int xsw = (lrow & 7) << 3;

  unsigned nwg = gridDim.x * gridDim.y;
  unsigned wg = blockIdx.y * gridDim.x + blockIdx.x;
  {
    unsigned q = nwg >> 3, r = nwg & 7u;
    unsigned xcd = wg & 7u, idx = wg >> 3;
    wg = (xcd < r ? xcd * (q + 1) : r * (q + 1) + (xcd - r) * q) + idx;
  }
  const long m0 = (long)(wg % gridDim.x) * 256;
  const long n0 = (long)(wg / gridDim.x) * 256;

  int crow[4], csrc[4];
#pragma unroll
  for (int j = 0; j < 4; ++j) {
    int c = tid + j * 512;
    crow[j] = c >> 3;
    csrc[j] = ((c & 7) * 8) ^ ((crow[j] & 7) << 3);
  }

  auto STAGE = [&](int buf, int t) {
    const long k0 = (long)t * 64;
    ushort_t* dstA = sh + buf * 32768;
    ushort_t* dstB = dstA + 16384;
#pragma unroll
    for (int j = 0; j < 4; ++j)
      gload_lds16(A + (m0 + crow[j]) * lda + k0 + csrc[j], dstA + (tid + j * 512) * 8);
#pragma unroll
    for (int j = 0; j < 4; ++j)
      gload_lds16(B + (n0 + crow[j]) * ldb + k0 + csrc[j], dstB + (tid + j * 512) * 8);
  };

  f32x4 acc[8][4] = {};
  const int nt = Kpad >> 6;

  STAGE(0, 0);
  STAGE(1, 1);
  asm volatile("s_waitcnt vmcnt(8)" ::: "memory");
  rbar();

  for (int t = 0; t < nt; ++t) {
    const ushort_t* As = sh + (t & 1) * 32768;
    const ushort_t* Bs = As + 16384;
#pragma unroll
    for (int kk = 0; kk < 2; ++kk) {
      bf16x8 af[8], bfr[4];
      const int co = (kk * 32 + hi * 8) ^ xsw;
#pragma unroll
      for (int mi = 0; mi < 8; ++mi)
        af[mi] = *(const bf16x8*)(As + (wr * 128 + mi * 16 + lrow) * 64 + co);
#pragma unroll
      for (int ni = 0; ni < 4; ++ni)
        bfr[ni] = *(const bf16x8*)(Bs + (wc * 64 + ni * 16 + lrow) * 64 + co);
      __builtin_amdgcn_s_setprio(1);
#pragma unroll
      for (int mi = 0; mi < 8; ++mi)
#pragma unroll
        for (int ni = 0; ni < 4; ++ni)
          acc[mi][ni] = __builtin_amdgcn_mfma_f32_16x16x32_bf16(af[mi], bfr[ni], acc[mi][ni], 0, 0, 0);
      __builtin_amdgcn_s_setprio(0);
    }
    if (t + 2 < nt) {
      rbar();
      STAGE(t & 1, t + 2);
      asm volatile("s_waitcnt vmcnt(8)" ::: "memory");
      rbar();
    } else if (t + 1 < nt) {
      rbar();
      asm volatile("s_waitcnt vmcnt(0)" ::: "memory");
      rbar();
    }
  }

  const int rbase = hi * 4;
#pragma unroll
  for (int ni = 0; ni < 4; ni++) {
    int gcol = (int)n0 + wc * 64 + ni * 16 + lrow;
    if (gcol < N) {
      float badd = 0.f;
      if (bias0) badd += bias0[gcol];
      if (bias1) badd += bias1[gcol];
#pragma unroll
      for (int mi = 0; mi < 8; mi++) {
#pragma unroll
        for (int r = 0; r < 4; r++) {
          long grow = m0 + wr * 128 + mi * 16 + rbase + r;
          float v = acc[mi][ni][r] + badd;
          if (F32OUT) ((float*)Cv)[grow * ldc + gcol] = v;
          else        ((ushort_t*)Cv)[grow * ldc + gcol] = f2b(v);
        }
      }
    }
  }
}

// =====================================================================
// Persistent LSTM layer (r14 form; poll backoff reduced to s_sleep(2))
// =====================================================================
__global__ __launch_bounds__(256) void lstm_layer(
    ushort_t* __restrict__ hs,        // [101][64][1152] bf16
    const ushort_t* __restrict__ G,   // [6400][4608] bf16
    const ushort_t* __restrict__ Whh, // padded [4608][1152] bf16
    const float* __restrict__ c_in,   // [64][1150] f32
    unsigned* __restrict__ flags)     // 72 lines of 128B
{
  extern __shared__ ushort_t Bsh[];
  const int tid = threadIdx.x;
  const int w = tid >> 6, l = tid & 63;
  const int us = blockIdx.x;
  const int lrow = l & 15, hi = l >> 4, lk = hi * 8;
  const int u = us * 16 + lrow;
  const int usafe = (u < 1150) ? u : 0;
  const int row0 = w * 16 + hi * 4;
  const int x7 = lrow & 7;
  const int start = us >> 1;

  for (int ci = tid; ci < 9216; ci += 256) {
    int gate = ci / 2304;
    int rem  = ci - gate * 2304;
    int row  = rem / 144;
    int c    = rem - row * 144;
    bf16x8 v = *(const bf16x8*)(Whh + ((long)(gate * 1150 + us * 16 + row)) * 1152 + c * 8);
    *(bf16x8*)(Bsh + (((gate * 16 + row) * 144) + (c ^ (row & 7))) * 8) = v;
  }
  const ushort_t* Bg0 = Bsh + ((0 * 16 + lrow) * 144) * 8;
  const ushort_t* Bg1 = Bsh + ((1 * 16 + lrow) * 144) * 8;
  const ushort_t* Bg2 = Bsh + ((2 * 16 + lrow) * 144) * 8;
  const ushort_t* Bg3 = Bsh + ((3 * 16 + lrow) * 144) * 8;

  f32x4 cc = {};
  if (u < 1150) {
#pragma unroll
    for (int r = 0; r < 4; ++r) cc[r] = c_in[(row0 + r) * 1150 + u];
  }
  __syncthreads();

  const int s1 = l, s2 = 64 + (l & 7);

  for (int t = 0; t < 100; ++t) {
    ushort_t gvv[16];
    {
      const ushort_t* gp = G + ((long)t * 64 + row0) * 4608 + usafe;
#pragma unroll
      for (int r = 0; r < 4; ++r)
#pragma unroll
        for (int g = 0; g < 4; ++g)
          gvv[r * 4 + g] = gp[(long)r * 4608 + g * 1150];
    }

    if (t > 0) {
      if (w == 0) {
        const unsigned tt = (unsigned)t;
        unsigned f1 = (s1 == us) ? tt :
            __hip_atomic_load(flags + (s1 << 5), __ATOMIC_RELAXED, __HIP_MEMORY_SCOPE_AGENT);
        unsigned f2 = (s2 == us) ? tt :
            __hip_atomic_load(flags + (s2 << 5), __ATOMIC_RELAXED, __HIP_MEMORY_SCOPE_AGENT);
        unsigned long long p1 = __ballot(f1 >= tt);
        unsigned long long p2 = __ballot(f2 >= tt);
        while ((p1 & p2) != ~0ull) {
          __builtin_amdgcn_s_sleep(2);   // 128-cy backoff (traffic is tiny now)
          if (!((p1 >> l) & 1))
            f1 = __hip_atomic_load(flags + (s1 << 5), __ATOMIC_RELAXED, __HIP_MEMORY_SCOPE_AGENT);
          if (!((p2 >> l) & 1))
            f2 = __hip_atomic_load(flags + (s2 << 5), __ATOMIC_RELAXED, __HIP_MEMORY_SCOPE_AGENT);
          p1 = __ballot(f1 >= tt);
          p2 = __ballot(f2 >= tt);
        }
      }
      __syncthreads();
      asm volatile("" ::: "memory");
    }

    const ushort_t* hp = hs + (long)t * 73728 + (long)(w * 16 + lrow) * 1152 + lk;
    f32x4 a0 = {}, a1 = {}, a2 = {}, a3 = {};

    bf16x8 A0[9], A1[9];
    auto ldg = [&](bf16x8* buf, int g) {
#pragma unroll
      for (int i = 0; i < 9; ++i) {
        int kc = start + g * 9 + i; if (kc >= 36) kc -= 36;
        buf[i] = *(const bf16x8*)(hp + kc * 32);
      }
    };
    auto cons = [&](const bf16x8* buf, int g) {
#pragma unroll
      for (int i = 0; i < 9; ++i) {
        int kc = start + g * 9 + i; if (kc >= 36) kc -= 36;
        int pc8 = ((kc * 4 + hi) ^ x7) * 8;
        a0 = __builtin_amdgcn_mfma_f32_16x16x32_bf16(buf[i], *(const bf16x8*)(Bg0 + pc8), a0, 0, 0, 0);
        a1 = __builtin_amdgcn_mfma_f32_16x16x32_bf16(buf[i], *(const bf16x8*)(Bg1 + pc8), a1, 0, 0, 0);
        a2 = __builtin_amdgcn_mfma_f32_16x16x32_bf16(buf[i], *(const bf16x8*)(Bg2 + pc8), a2, 0, 0, 0);
        a3 = __builtin_amdgcn_mfma_f32_16x16x32_bf16(buf[i], *(const bf16x8*)(Bg3 + pc8), a3, 0, 0, 0);
      }
    };
    ldg(A0, 0); ldg(A1, 1);
    cons(A0, 0); ldg(A0, 2);
    cons(A1, 1); ldg(A1, 3);
    cons(A0, 2);
    cons(A1, 3);

    if (u < 1150) {
#pragma unroll
      for (int r = 0; r < 4; ++r) {
        float iv = a0[r] + b2f(gvv[r * 4 + 0]);
        float fv = a1[r] + b2f(gvv[r * 4 + 1]);
        float gg = a2[r] + b2f(gvv[r * 4 + 2]);
        float ov = a3[r] + b2f(gvv[r * 4 + 3]);
        float cn = sigm(fv) * cc[r] + sigm(iv) * tanhfast(gg);
        cc[r] = cn;
        float hv = sigm(ov) * tanhfast(cn);
        store_short_wt(hs + (long)(t + 1) * 73728 + (long)(row0 + r) * 1152 + u, f2b(hv));
      }
    }

    if (t != 99) {
      asm volatile("s_waitcnt vmcnt(0)" ::: "memory");
      __syncthreads();
      if (tid == 0) store_uint_wt(flags + (us << 5), (unsigned)(t + 1));
    }
  }
}

// =====================================================================
// Fused causal attention for one (t,b), VECTORIZED (bf16x8 loads):
// q fragment in registers (same h-subset for every s); scores via 16B k
// loads + wave shuffle reduce; PV with thread-owned 8-elem chunk and
// unrolled independent s-loads. hs2 pad cols are zero -> pads fall out.
// =====================================================================
__global__ __launch_bounds__(256) void attn_kernel(
    const ushort_t* __restrict__ hs2,  // base at hs[1]: [100][64][1152] bf16
    ushort_t* __restrict__ outp)       // [6400][1152] bf16
{
  __shared__ float sc[104];
  __shared__ float sinv;
  const int rowi = blockIdx.x;  // t*64 + b
  const int t = rowi >> 6, b = rowi & 63;
  const int tid = threadIdx.x;
  const int w = tid >> 6, l = tid & 63;

  // q fragments: 144 chunks of 8 elems; lane l owns chunks l, l+64, l+128(<144)
  const ushort_t* q = hs2 + (long)rowi * 1152;
  us8 q0 = *(const us8*)(q + l * 8);
  us8 q1 = *(const us8*)(q + (l + 64) * 8);
  us8 q2 = {};
  if (l < 16) q2 = *(const us8*)(q + (l + 128) * 8);

  for (int s = w; s <= t; s += 4) {
    const ushort_t* k = hs2 + (long)(s * 64 + b) * 1152;
    us8 k0 = *(const us8*)(k + l * 8);
    us8 k1 = *(const us8*)(k + (l + 64) * 8);
    float p = 0.f;
#pragma unroll
    for (int e = 0; e < 8; ++e)
      p += b2f(q0[e]) * b2f(k0[e]) + b2f(q1[e]) * b2f(k1[e]);
    if (l < 16) {
      us8 k2 = *(const us8*)(k + (l + 128) * 8);
#pragma unroll
      for (int e = 0; e < 8; ++e) p += b2f(q2[e]) * b2f(k2[e]);
    }
    for (int off = 32; off; off >>= 1) p += __shfl_down(p, off);
    if (l == 0) sc[s] = p;
  }
  __syncthreads();

  if (w == 0) {
    float m = -1e30f;
    for (int s = l; s <= t; s += 64) m = fmaxf(m, sc[s]);
    for (int off = 32; off; off >>= 1) m = fmaxf(m, __shfl_down(m, off));
    m = __shfl(m, 0);
    float sum = 0.f;
    for (int s = l; s <= t; s += 64) { float e = __expf(sc[s] - m); sc[s] = e; sum += e; }
    for (int off = 32; off; off >>= 1) sum += __shfl_down(sum, off);
    if (l == 0) sinv = 1.f / sum;
  }
  __syncthreads();

  // PV: thread tid owns chunk tid (144 active threads)
  if (tid < 144) {
    const float si = sinv;
    float acc[8] = {};
    const ushort_t* vbase = hs2 + (long)b * 1152 + tid * 8;
#pragma unroll 4
    for (int s = 0; s <= t; ++s) {
      us8 v = *(const us8*)(vbase + (long)s * 73728);
      float ps = sc[s];
#pragma unroll
      for (int e = 0; e < 8; ++e) acc[e] += ps * b2f(v[e]);
    }
    union { us8 v; ushort_t s[8]; } pk;
#pragma unroll
    for (int e = 0; e < 8; ++e) pk.s[e] = f2b(acc[e] * si);
    *(us8*)(outp + (long)rowi * 1152 + tid * 8) = pk.v;
  }
}

// ---------- f32 -> bf16 conversion helpers ----------
__global__ void embed_kernel(const int* __restrict__ in1, const int* __restrict__ in2,
                             const float* __restrict__ emb, ushort_t* __restrict__ x0)
{
  int rowi = blockIdx.x;
  int l = threadIdx.x;    // 64 threads
  long r1 = (long)in1[rowi] * 400, r2 = (long)in2[rowi] * 400;
  ushort_t* d = x0 + (long)rowi * 832;   // K padded 800 -> 832 (zeros)
  for (int c = l; c < 832; c += 64) {
    ushort_t v = 0;
    if (c < 800) v = f2b(c < 400 ? emb[r1 + c] : emb[r2 + c - 400]);
    d[c] = v;
  }
}

__global__ void pad_convert(const float* __restrict__ in, ushort_t* __restrict__ out,
                            int R, int Cin, int total, int Cp)
{
  int idx = blockIdx.x * 256 + threadIdx.x;
  if (idx >= total) return;
  int r = idx / Cp, c = idx - r * Cp;
  float v = (r < R && c < Cin) ? in[(long)r * Cin + c] : 0.f;
  out[idx] = f2b(v);
}

__global__ void init_state(const float* __restrict__ h_in,
                           ushort_t* __restrict__ hs, unsigned* __restrict__ flags)
{
  int idx = blockIdx.x * 256 + threadIdx.x;
  if (idx < 72 * 32) flags[idx] = 0u;
  if (idx < 64 * 1152) {
    int b = idx / 1152, c = idx - b * 1152;
    hs[idx] = (c < 1150) ? f2b(h_in[b * 1150 + c]) : (ushort_t)0;
  }
  if (idx < 100 * 128) {
    int t = idx >> 7, r = idx & 127, b = r >> 1, k = r & 1;
    hs[(long)(t + 1) * 73728 + b * 1152 + 1150 + k] = 0;
  }
}

// =====================================================================
extern "C" void kernel_launch(void* const* d_in, const int* in_sizes, int n_in,
                              void* d_out, int out_size, void* d_ws, size_t ws_size,
                              hipStream_t stream) {
  (void)in_sizes; (void)n_in; (void)out_size; (void)ws_size;
  const int* input  = (const int*)d_in[0];
  const int* input2 = (const int*)d_in[1];
  const float* h_in[3] = {(const float*)d_in[2], (const float*)d_in[4], (const float*)d_in[6]};
  const float* c_in[3] = {(const float*)d_in[3], (const float*)d_in[5], (const float*)d_in[7]};
  const float* emb_W = (const float*)d_in[8];
  const float* W_ih[3] = {(const float*)d_in[9],  (const float*)d_in[13], (const float*)d_in[17]};
  const float* W_hh[3] = {(const float*)d_in[10], (const float*)d_in[14], (const float*)d_in[18]};
  const float* b_ih[3] = {(const float*)d_in[11], (const float*)d_in[15], (const float*)d_in[19]};
  const float* b_hh[3] = {(const float*)d_in[12], (const float*)d_in[16], (const float*)d_in[20]};
  const float* dec_W = (const float*)d_in[21];
  const float* dec_b = (const float*)d_in[22];
  float* out = (float*)d_out;

  hipFuncSetAttribute((const void*)lstm_layer,
                      hipFuncAttributeMaxDynamicSharedMemorySize, 147456);
  hipFuncSetAttribute(reinterpret_cast<const void*>(gemm256<false>),
                      hipFuncAttributeMaxDynamicSharedMemorySize, 131072);
  hipFuncSetAttribute(reinterpret_cast<const void*>(gemm256<true>),
                      hipFuncAttributeMaxDynamicSharedMemorySize, 131072);

  // ---- workspace: decoder-phase buffers + flags ----
  char* base = (char*)d_ws;
  size_t off = 0;
  auto walloc = [&](size_t bytes) { char* r = base + off; off += (bytes + 255) & ~(size_t)255; return r; };
  ushort_t* decWp = (ushort_t*)walloc(33280ull * 1152 * 2);   // 76,677,120
  ushort_t* attnB = (ushort_t*)walloc(6400ull * 1152 * 2);    // 14,745,600
  unsigned* flags = (unsigned*)walloc(72 * 128 + 256);

  // ---- layer-phase scratch inside d_out (all dead before decoder GEMM) ----
  char* ob = (char*)d_out;
  ushort_t* G   = (ushort_t*)(ob + 0);            // 58,982,400
  ushort_t* x0  = (ushort_t*)(ob + 58982400);     // 6400*832*2 = 10,649,600
  ushort_t* Wp  = (ushort_t*)(ob + 69632000);     // 10,616,832
  ushort_t* Whp = (ushort_t*)(ob + 80248832);     // 10,616,832
  ushort_t* hsA = (ushort_t*)(ob + 90865664);     // 14,893,056
  ushort_t* hsB = (ushort_t*)(ob + 105758720);    // -> end 120,651,776

  embed_kernel<<<6400, 64, 0, stream>>>(input, input2, emb_W, x0);

  ushort_t* hcur[3] = {hsA, hsB, hsA};
  const ushort_t* X = x0;
  int lda = 832, Kp = 832;
  for (int lyr = 0; lyr < 3; lyr++) {
    if (lyr == 0) {
      int tot = 4608 * 832;
      pad_convert<<<(tot + 255) / 256, 256, 0, stream>>>(W_ih[0], Wp, 4600, 800, tot, 832);
    } else {
      int tot = 4608 * 1152;
      pad_convert<<<(tot + 255) / 256, 256, 0, stream>>>(W_ih[lyr], Wp, 4600, 1150, tot, 1152);
    }
    {
      int tot = 4608 * 1152;
      pad_convert<<<(tot + 255) / 256, 256, 0, stream>>>(W_hh[lyr], Whp, 4600, 1150, tot, 1152);
    }
    gemm256<false><<<dim3(25, 18), 512, 131072, stream>>>(X, Wp, (void*)G, b_ih[lyr], b_hh[lyr],
                                                          lda, Kp, 4608L, Kp, 4600);
    init_state<<<288, 256, 0, stream>>>(h_in[lyr], hcur[lyr], flags);
    lstm_layer<<<72, 256, 147456, stream>>>(hcur[lyr], G, Whp, c_in[lyr], flags);
    X = hcur[lyr] + 73728;
    lda = 1152; Kp = 1152;
  }

  attn_kernel<<<6400, 256, 0, stream>>>(hsA + 73728, attnB);

  {
    int tot = 33280 * 1152;
    pad_convert<<<(tot + 255) / 256, 256, 0, stream>>>(dec_W, decWp, 33278, 1150, tot, 1152);
  }

  gemm256<true><<<dim3(25, 130), 512, 131072, stream>>>(attnB, decWp, (void*)out, dec_b, nullptr,
                                                        1152, 1152, 33278L, 1152, 33278);
}